// Round 1
// 228.685 us; speedup vs baseline: 1.0005x; 1.0005x over previous
//
#include <hip/hip_runtime.h>

constexpr int BATCH = 2048;
constexpr int NHID  = 512;
constexpr int H0    = 256;
constexpr int H1    = 256;
constexpr int SMAX  = 32;          // tile capacity: 4 predicated groups of 8
constexpr int KS    = NHID / 4;    // 128 rows per K-split wave

// One block per parent p (grid = 256), 512 threads = 8 waves.
// Waves 0-3: bottom pass; wave kw streams botW[p] rows [128kw, 128kw+128).
// Waves 4-7: top pass; same K-split over topW.
// Each wave computes partial GEMV for up to 32 samples (4 uniform-predicated
// groups of 8 -> static acc indices). K-partials reduced via chunked LDS
// buffers; waves 0/4 run the verified wave-local shuffle softmax.
__global__ __launch_bounds__(512, 2) void hs_ksplit(
    const float* __restrict__ x,        // [B, NHID]
    const int*   __restrict__ labels,   // [B]
    const int*   __restrict__ parents,  // [B]
    const float* __restrict__ topW,     // [NHID, H0]
    const float* __restrict__ topb,     // [H0]
    const float* __restrict__ botW,     // [H0, NHID, H1]
    const float* __restrict__ botb,     // [H0, H1]
    float*       __restrict__ out)      // [B]
{
    const int p  = blockIdx.x;
    const int t  = threadIdx.x;        // 0..511
    const int g  = t >> 6;             // wave 0..7
    const int l  = t & 63;
    const int kw = g & 3;              // K-slice index within pass
    const bool bot = (g < 4);          // waves 0-3 bottom, 4-7 top

    __shared__ int list[BATCH];                     // 8 KB
    __shared__ int wcnt[8];
    __shared__ __align__(16) float  xs[SMAX][NHID]; // 64 KB
    __shared__ __align__(16) float4 redB[3][4][64]; // 12 KB
    __shared__ __align__(16) float4 redT[3][4][64]; // 12 KB
    __shared__ float psm[2][SMAX];

    // ---- deterministic list build: 4 chunks of 512, ballot prefix scan
    int running = 0;
    for (int c = 0; c < BATCH; c += 512) {
        const bool match = (parents[c + t] == p);
        const unsigned long long mask = __ballot(match);
        if (l == 0) wcnt[g] = __popcll(mask);
        __syncthreads();
        int off = running;
        #pragma unroll
        for (int w = 0; w < 8; ++w) {
            const int cw = wcnt[w];
            if (w < g) off += cw;
            running += cw;
        }
        if (match)
            list[off + __popcll(mask & ((1ull << l) - 1ull))] = c + t;
        __syncthreads();   // wcnt reused next chunk
    }
    const int n = running;
    if (n == 0) return;    // uniform exit

    const float* Wbase = bot
        ? botW + (size_t)p * NHID * H1 + (size_t)kw * KS * H1
        : topW + (size_t)kw * KS * H0;
    const float4 b4 = bot ? *(const float4*)(botb + (size_t)p * H1 + 4 * l)
                          : *(const float4*)(topb + 4 * l);
    const int koff = kw * KS;

    for (int base = 0; base < n; base += SMAX) {   // normally exactly 1 tile
        const int rem  = min(SMAX, n - base);
        const int ngrp = (rem + 7) >> 3;           // active groups of 8
        const int nrow = 8 * ngrp;

        // ---- stage x rows (padded slots replicate last real sample)
        for (int s0 = 0; s0 < nrow; s0 += 4) {
            const int row = s0 + (t >> 7);
            const int idx = list[base + min(row, rem - 1)];
            ((float4*)xs[row])[t & 127] =
                ((const float4*)(x + (size_t)idx * NHID))[t & 127];
        }
        __syncthreads();   // xs ready

        // ---- K-slice register GEMV: up to 32 samples, 4 classes/lane
        float4 acc[4][8];
        #pragma unroll
        for (int gr = 0; gr < 4; ++gr)
            #pragma unroll
            for (int s = 0; s < 8; ++s)
                acc[gr][s] = make_float4(0.f, 0.f, 0.f, 0.f);

        const float* Wp = Wbase + 4 * l;
        float4 ring[8];
        #pragma unroll
        for (int i = 0; i < 8; ++i)
            ring[i] = *(const float4*)(Wp + (size_t)i * 256);

        for (int d = 0; d < KS; d += 8) {
            #pragma unroll
            for (int h = 0; h < 2; ++h) {
                const int dd = d + 4 * h;
                const float4 w0 = ring[4 * h + 0], w1 = ring[4 * h + 1];
                const float4 w2 = ring[4 * h + 2], w3 = ring[4 * h + 3];
                if (dd + 8 < KS) {
                    #pragma unroll
                    for (int i = 0; i < 4; ++i)
                        ring[4 * h + i] =
                            *(const float4*)(Wp + (size_t)(dd + 8 + i) * 256);
                }
                #pragma unroll
                for (int gr = 0; gr < 4; ++gr) {
                    if (gr < ngrp) {   // wave-uniform predication, static idx
                        #pragma unroll
                        for (int s = 0; s < 8; ++s) {
                            const float4 xv =
                                *(const float4*)&xs[8 * gr + s][koff + dd];
                            float4 a = acc[gr][s];
                            a.x = fmaf(xv.x, w0.x, a.x); a.y = fmaf(xv.x, w0.y, a.y);
                            a.z = fmaf(xv.x, w0.z, a.z); a.w = fmaf(xv.x, w0.w, a.w);
                            a.x = fmaf(xv.y, w1.x, a.x); a.y = fmaf(xv.y, w1.y, a.y);
                            a.z = fmaf(xv.y, w1.z, a.z); a.w = fmaf(xv.y, w1.w, a.w);
                            a.x = fmaf(xv.z, w2.x, a.x); a.y = fmaf(xv.z, w2.y, a.y);
                            a.z = fmaf(xv.z, w2.z, a.z); a.w = fmaf(xv.z, w2.w, a.w);
                            a.x = fmaf(xv.w, w3.x, a.x); a.y = fmaf(xv.w, w3.y, a.y);
                            a.z = fmaf(xv.w, w3.z, a.z); a.w = fmaf(xv.w, w3.w, a.w);
                            acc[gr][s] = a;
                        }
                    }
                }
            }
        }

        // ---- chunked cross-wave reduction (4 samples/round) + softmax
        float4 (*red)[4][64] = bot ? redB : redT;
        #pragma unroll
        for (int gr = 0; gr < 4; ++gr) {
            if (gr < ngrp) {   // uniform across block
                #pragma unroll
                for (int hf = 0; hf < 2; ++hf) {
                    if (kw != 0) {
                        #pragma unroll
                        for (int si = 0; si < 4; ++si)
                            red[kw - 1][si][l] = acc[gr][4 * hf + si];
                    }
                    __syncthreads();   // partials visible
                    if (kw == 0) {     // wave 0 (bottom) / wave 4 (top)
                        #pragma unroll
                        for (int si = 0; si < 4; ++si) {
                            const int s = 8 * gr + 4 * hf + si;
                            const float4 r0 = red[0][si][l];
                            const float4 r1 = red[1][si][l];
                            const float4 r2 = red[2][si][l];
                            float4 v = acc[gr][4 * hf + si];
                            v.x += r0.x + r1.x + r2.x + b4.x;
                            v.y += r0.y + r1.y + r2.y + b4.y;
                            v.z += r0.z + r1.z + r2.z + b4.z;
                            v.w += r0.w + r1.w + r2.w + b4.w;

                            float m = fmaxf(fmaxf(v.x, v.y), fmaxf(v.z, v.w));
                            #pragma unroll
                            for (int off = 32; off > 0; off >>= 1)
                                m = fmaxf(m, __shfl_xor(m, off, 64));

                            const float ex = expf(v.x - m), ey = expf(v.y - m);
                            const float ez = expf(v.z - m), ew = expf(v.w - m);
                            float sum = (ex + ey) + (ez + ew);
                            #pragma unroll
                            for (int off = 32; off > 0; off >>= 1)
                                sum += __shfl_xor(sum, off, 64);

                            const int tgt =
                                bot ? labels[list[base + min(s, rem - 1)]] : p;
                            const int k = tgt & 3;
                            const float ev = (k == 0) ? ex : (k == 1) ? ey
                                           : (k == 2) ? ez : ew;
                            if (l == (tgt >> 2))
                                psm[bot ? 1 : 0][s] = ev / sum;
                        }
                    }
                    __syncthreads();   // red buffer reuse / psm publish
                }
            }
        }

        if (t < rem) {
            const int idx = list[base + t];
            out[idx] = psm[0][t] * psm[1][t];
        }
        __syncthreads();   // xs/psm safe to overwrite next tile
    }
}

extern "C" void kernel_launch(void* const* d_in, const int* in_sizes, int n_in,
                              void* d_out, int out_size, void* d_ws, size_t ws_size,
                              hipStream_t stream) {
    const float* x       = (const float*)d_in[0];
    const int*   labels  = (const int*)  d_in[1];
    const int*   parents = (const int*)  d_in[2];
    const float* topW    = (const float*)d_in[3];
    const float* topb    = (const float*)d_in[4];
    const float* botW    = (const float*)d_in[5];
    const float* botb    = (const float*)d_in[6];
    float*       out     = (float*)d_out;

    hs_ksplit<<<H0, 512, 0, stream>>>(x, labels, parents,
                                      topW, topb, botW, botb, out);
}